// Round 8
// baseline (93.675 us; speedup 1.0000x reference)
//
#include <hip/hip_runtime.h>
#include <math.h>

// Problem constants (from reference: N=512, D=4096, fp32).
#define PN 512
#define PD 4096

// bf16 MFMA split-K config. R8: KSZ 8->16 (4 stages/block, 1024 blocks = 4/CU).
#define KSZ 16
#define KCHUNK (PD / KSZ)     // 256
#define BK 64                 // K per LDS stage
#define NSTAGE (KCHUNK / BK)  // 4

// ws float-index layout:
//   [0,512) sa | [512,1024) sp | [1024,1536) dd
//   1536 sum(f32) | 1537 cnt(u32) | 1538 done(u32)
//   byte 8192:            ah bf16 [512][4096]  (4 MB)
//   byte 8192+4MB:        ph bf16 [512][4096]  (4 MB)
//   float WS_PART_FLOAT:  split-K partials f32 [KSZ][512][512] (16 MB)
#define F_SA 0
#define F_SP 512
#define F_DD 1024
#define F_SUM 1536
#define F_CNT 1537
#define F_DONE 1538
#define WS_AH_BYTES 8192
#define WS_PH_BYTES (8192 + 4194304)
#define WS_PART_FLOAT 2099200  // (8192 + 2*4194304)/4
#define WS_NEED ((size_t)WS_PART_FLOAT * 4 + (size_t)KSZ * PN * PN * 4)

typedef __attribute__((ext_vector_type(8))) short short8;
typedef __attribute__((ext_vector_type(4))) float floatx4;

static __device__ __forceinline__ unsigned short f2bf(float x) {
    unsigned int u = __float_as_uint(x);
    u += 0x7fffu + ((u >> 16) & 1u);
    return (unsigned short)(u >> 16);
}

static __device__ __forceinline__ void load16_lds(const void* gp, void* lp) {
    __builtin_amdgcn_global_load_lds(
        (const __attribute__((address_space(1))) unsigned int*)gp,
        (__attribute__((address_space(3))) unsigned int*)lp,
        16, 0, 0);
}

struct ushort4s { unsigned short x, y, z, w; };

// ---------------- prep: norms + diag dist + fp32->bf16 + counter zeroing ----------------
__global__ __launch_bounds__(256) void taw_prep_kernel(
        const float* __restrict__ a, const float* __restrict__ p,
        float* __restrict__ ws) {
    const int i = blockIdx.x;
    const int t = threadIdx.x;
    if (i == 0 && t < 64) ((unsigned int*)ws)[1536 + t] = 0u;  // sum/cnt/done
    const float4* a4 = (const float4*)(a + (size_t)i * PD);
    const float4* p4 = (const float4*)(p + (size_t)i * PD);
    unsigned short* ah = (unsigned short*)((char*)ws + WS_AH_BYTES) + (size_t)i * PD;
    unsigned short* ph = (unsigned short*)((char*)ws + WS_PH_BYTES) + (size_t)i * PD;
    float sa = 0.f, sp = 0.f, dp = 0.f;
#pragma unroll
    for (int c = 0; c < 4; ++c) {
        const int e = c * 256 + t;
        float4 av = a4[e];
        float4 pv = p4[e];
        sa += av.x * av.x + av.y * av.y + av.z * av.z + av.w * av.w;
        sp += pv.x * pv.x + pv.y * pv.y + pv.z * pv.z + pv.w * pv.w;
        dp += av.x * pv.x + av.y * pv.y + av.z * pv.z + av.w * pv.w;
        ushort4s ab = {f2bf(av.x), f2bf(av.y), f2bf(av.z), f2bf(av.w)};
        ushort4s pb = {f2bf(pv.x), f2bf(pv.y), f2bf(pv.z), f2bf(pv.w)};
        *(ushort4s*)(ah + (size_t)e * 4) = ab;
        *(ushort4s*)(ph + (size_t)e * 4) = pb;
    }
#pragma unroll
    for (int off = 32; off > 0; off >>= 1) {
        sa += __shfl_down(sa, off, 64);
        sp += __shfl_down(sp, off, 64);
        dp += __shfl_down(dp, off, 64);
    }
    __shared__ float red[3][4];
    const int wave = t >> 6;
    if ((t & 63) == 0) { red[0][wave] = sa; red[1][wave] = sp; red[2][wave] = dp; }
    __syncthreads();
    if (t == 0) {
        sa = red[0][0] + red[0][1] + red[0][2] + red[0][3];
        sp = red[1][0] + red[1][1] + red[1][2] + red[1][3];
        dp = red[2][0] + red[2][1] + red[2][2] + red[2][3];
        float d2 = sa - 2.f * dp + sp;
        d2 = fmaxf(d2, 0.f);
        ws[F_SA + i] = sa;
        ws[F_SP + i] = sp;
        ws[F_DD + i] = (d2 == 0.f) ? 0.f : sqrtf(d2);
    }
}

// ---------------- bf16 MFMA split-K GEMM: 64x64 tile, Kchunk 256, 4 stages ----------------
// grid (8, 8, KSZ), block 256 (4 waves; wave w -> 32x32 quadrant (w>>1, w&1)).
// LDS in fragment order: lds[A/B][group g][lane][8 bf16]. (R3-proven structure.)
__global__ __launch_bounds__(256) void taw_mfma_kernel(float* __restrict__ ws) {
    __shared__ short lds[2][8][64][8];  // 16 KB
    const unsigned short* ah = (const unsigned short*)((const char*)ws + WS_AH_BYTES);
    const unsigned short* ph = (const unsigned short*)((const char*)ws + WS_PH_BYTES);
    const int t = threadIdx.x;
    const int lane = t & 63;
    const int w = t >> 6;
    const int wm = w >> 1, wn = w & 1;
    const int i0 = blockIdx.y * 64;
    const int j0 = blockIdx.x * 64;
    const int kz = blockIdx.z * KCHUNK;

    floatx4 acc[2][2] = {{{0.f, 0.f, 0.f, 0.f}, {0.f, 0.f, 0.f, 0.f}},
                         {{0.f, 0.f, 0.f, 0.f}, {0.f, 0.f, 0.f, 0.f}}};

    for (int st = 0; st < NSTAGE; ++st) {
        const int kb = kz + st * BK;
        __syncthreads();
#pragma unroll
        for (int q = 0; q < 2; ++q) {
            const int g = 2 * w + q;
            const int row = ((g & 3) << 4) + (lane & 15);
            const int kk = kb + ((((g >> 2) << 2) + (lane >> 4)) << 3);
            load16_lds(ah + (size_t)(i0 + row) * PD + kk, &lds[0][g][0][0]);
            load16_lds(ph + (size_t)(j0 + row) * PD + kk, &lds[1][g][0][0]);
        }
        __syncthreads();
#pragma unroll
        for (int s2 = 0; s2 < 2; ++s2) {
            short8 af0 = *(const short8*)&lds[0][s2 * 4 + wm * 2 + 0][lane][0];
            short8 af1 = *(const short8*)&lds[0][s2 * 4 + wm * 2 + 1][lane][0];
            short8 bf0 = *(const short8*)&lds[1][s2 * 4 + wn * 2 + 0][lane][0];
            short8 bf1 = *(const short8*)&lds[1][s2 * 4 + wn * 2 + 1][lane][0];
            acc[0][0] = __builtin_amdgcn_mfma_f32_16x16x32_bf16(af0, bf0, acc[0][0], 0, 0, 0);
            acc[0][1] = __builtin_amdgcn_mfma_f32_16x16x32_bf16(af0, bf1, acc[0][1], 0, 0, 0);
            acc[1][0] = __builtin_amdgcn_mfma_f32_16x16x32_bf16(af1, bf0, acc[1][0], 0, 0, 0);
            acc[1][1] = __builtin_amdgcn_mfma_f32_16x16x32_bf16(af1, bf1, acc[1][1], 0, 0, 0);
        }
    }

    // C/D layout: col=lane&15, row=(lane>>4)*4+reg [m89-verified]
    float* part = ws + WS_PART_FLOAT + (size_t)blockIdx.z * (PN * PN);
    const int jj = j0 + wn * 32 + (lane & 15);
    const int ib = i0 + wm * 32 + ((lane >> 4) << 2);
#pragma unroll
    for (int rm = 0; rm < 2; ++rm)
#pragma unroll
        for (int rn = 0; rn < 2; ++rn)
#pragma unroll
            for (int r = 0; r < 4; ++r)
                part[(size_t)(ib + rm * 16 + r) * PN + jj + rn * 16] = acc[rm][rn][r];
}

// ---------------- reduce partials + epilogue + election finalize ----------------
__global__ __launch_bounds__(256) void taw_reduce_kernel(float* __restrict__ ws,
                                                         float* __restrict__ out) {
    unsigned int* wsu = (unsigned int*)ws;
    const int g = blockIdx.x * 256 + threadIdx.x;  // one float4 of the 512x512 dot
    const float4* part4 = (const float4*)(ws + WS_PART_FLOAT);
    float4 dot = part4[g];
#pragma unroll
    for (int ks = 1; ks < KSZ; ++ks) {
        const float4 v = part4[((size_t)ks << 16) + g];
        dot.x += v.x; dot.y += v.y; dot.z += v.z; dot.w += v.w;
    }
    const int flat = g << 2;
    const int i = flat >> 9;
    const int j = flat & 511;
    const float sa = ws[F_SA + i];
    const float dd = ws[F_DD + i];
    const float4 sp4 = *(const float4*)(ws + F_SP + j);
    const float dotr[4] = {dot.x, dot.y, dot.z, dot.w};
    const float spr[4] = {sp4.x, sp4.y, sp4.z, sp4.w};
    float lsum = 0.f;
    unsigned int lcnt = 0;
#pragma unroll
    for (int c = 0; c < 4; ++c) {
        const int jj = j + c;
        float d2 = sa - 2.f * dotr[c] + spr[c];
        d2 = fmaxf(d2, 0.f);
        const float dist = (d2 == 0.f) ? 0.f : sqrtf(d2);
        const float v = (i != jj) ? fmaxf(dd - dist, 0.f) : 0.f;
        lsum += v;
        lcnt += (v > 1e-16f) ? 1u : 0u;
    }
#pragma unroll
    for (int off = 32; off > 0; off >>= 1) {
        lsum += __shfl_down(lsum, off, 64);
        lcnt += __shfl_down(lcnt, off, 64);
    }
    __shared__ float rsum[4];
    __shared__ unsigned int rcnt[4];
    const int t = threadIdx.x;
    if ((t & 63) == 0) { rsum[t >> 6] = lsum; rcnt[t >> 6] = lcnt; }
    __syncthreads();
    if (t == 0) {
        // Atomic-only protocol: atomics execute at the device coherence point;
        // consuming returned values forces retirement before the DONE bump.
        const float oldsum = atomicAdd(ws + F_SUM, rsum[0] + rsum[1] + rsum[2] + rsum[3]);
        const unsigned int oldcnt = atomicAdd(&wsu[F_CNT],
                                              rcnt[0] + rcnt[1] + rcnt[2] + rcnt[3]);
        unsigned int dep = __float_as_uint(oldsum) | oldcnt;
        asm volatile("" : "+v"(dep));  // opaque: keep the data dependency alive
        if (atomicAdd(&wsu[F_DONE], 1u + (dep & 0u)) == 255u) {
            const float s = atomicAdd(ws + F_SUM, 0.0f);        // coherent read
            const unsigned int c = atomicAdd(&wsu[F_CNT], 0u);  // coherent read
            out[0] = (float)((double)s / ((double)c + 1e-16));
        }
    }
}

// ---------------- fallback single-pass fp32 GEMM (proven path) ----------------
__global__ __launch_bounds__(256) void taw_gemm_loss_kernel(
        const float* __restrict__ A, const float* __restrict__ P,
        float* __restrict__ ws) {
    __shared__ float as[32][34];
    __shared__ float bs[32][34];
    const int tx = threadIdx.x;
    const int ty = threadIdx.y;
    const int t = ty * 16 + tx;
    const int i0 = blockIdx.y * 32;
    const int j0 = blockIdx.x * 32;
    const int sr = t >> 3;
    const int sk = (t & 7) * 4;
    const float* aptr = A + (size_t)(i0 + sr) * PD + sk;
    const float* pptr = P + (size_t)(j0 + sr) * PD + sk;
    float c00 = 0.f, c01 = 0.f, c10 = 0.f, c11 = 0.f;
    for (int k0 = 0; k0 < PD; k0 += 32) {
        float4 av = *(const float4*)(aptr + k0);
        float4 pv = *(const float4*)(pptr + k0);
        __syncthreads();
        as[sk + 0][sr] = av.x; as[sk + 1][sr] = av.y;
        as[sk + 2][sr] = av.z; as[sk + 3][sr] = av.w;
        bs[sk + 0][sr] = pv.x; bs[sk + 1][sr] = pv.y;
        bs[sk + 2][sr] = pv.z; bs[sk + 3][sr] = pv.w;
        __syncthreads();
#pragma unroll
        for (int kk = 0; kk < 32; ++kk) {
            const float2 a2 = *(const float2*)&as[kk][2 * ty];
            const float2 b2 = *(const float2*)&bs[kk][2 * tx];
            c00 = fmaf(a2.x, b2.x, c00);
            c01 = fmaf(a2.x, b2.y, c01);
            c10 = fmaf(a2.y, b2.x, c10);
            c11 = fmaf(a2.y, b2.y, c11);
        }
    }
    const int i = i0 + 2 * ty;
    const int j = j0 + 2 * tx;
    float cvals[2][2] = {{c00, c01}, {c10, c11}};
    float lsum = 0.f;
    unsigned int lcnt = 0;
#pragma unroll
    for (int dr = 0; dr < 2; ++dr)
#pragma unroll
        for (int dc = 0; dc < 2; ++dc) {
            const int ii = i + dr, jj = j + dc;
            float d2 = ws[F_SA + ii] - 2.f * cvals[dr][dc] + ws[F_SP + jj];
            d2 = fmaxf(d2, 0.f);
            const float dist = (d2 == 0.f) ? 0.f : sqrtf(d2);
            const float v = (ii != jj) ? fmaxf(ws[F_DD + ii] - dist, 0.f) : 0.f;
            lsum += v;
            lcnt += (v > 1e-16f) ? 1u : 0u;
        }
#pragma unroll
    for (int off = 32; off > 0; off >>= 1) {
        lsum += __shfl_down(lsum, off, 64);
        lcnt += __shfl_down(lcnt, off, 64);
    }
    __shared__ float rsum[4];
    __shared__ unsigned int rcnt[4];
    if ((t & 63) == 0) { rsum[t >> 6] = lsum; rcnt[t >> 6] = lcnt; }
    __syncthreads();
    if (t == 0) {
        atomicAdd(ws + F_SUM, rsum[0] + rsum[1] + rsum[2] + rsum[3]);
        atomicAdd(((unsigned int*)ws) + F_CNT, rcnt[0] + rcnt[1] + rcnt[2] + rcnt[3]);
    }
}

__global__ void taw_finalize_kernel(const float* __restrict__ ws,
                                    float* __restrict__ out) {
    const double s = (double)ws[F_SUM];
    const double c = (double)(((const unsigned int*)ws)[F_CNT]);
    out[0] = (float)(s / (c + 1e-16));
}

extern "C" void kernel_launch(void* const* d_in, const int* in_sizes, int n_in,
                              void* d_out, int out_size, void* d_ws, size_t ws_size,
                              hipStream_t stream) {
    (void)in_sizes; (void)n_in; (void)out_size;
    const float* a = (const float*)d_in[0];
    const float* p = (const float*)d_in[1];
    float* out = (float*)d_out;
    float* ws = (float*)d_ws;

    taw_prep_kernel<<<PN, 256, 0, stream>>>(a, p, ws);
    if (ws_size >= WS_NEED) {
        taw_mfma_kernel<<<dim3(8, 8, KSZ), 256, 0, stream>>>(ws);
        taw_reduce_kernel<<<256, 256, 0, stream>>>(ws, out);
    } else {
        taw_gemm_loss_kernel<<<dim3(16, 16), dim3(16, 16), 0, stream>>>(a, p, ws);
        taw_finalize_kernel<<<1, 1, 0, stream>>>(ws, out);
    }
}